// Round 16
// baseline (249.521 us; speedup 1.0000x reference)
//
#include <hip/hip_runtime.h>

#define F_IN  256
#define F_OUT 32

#define NPB       512        // nodes per bucket (2^9)
#define NPB_SHIFT 9
#define NB2MAX    256        // max buckets: supports N <= 131072
#define EPW       8192       // edges per WG: run len ~ EPW/196 = 42 ints ~ 2.6 lines
#define BCAP      10240      // bucket capacity (mean 8192, +22 sigma)

typedef __attribute__((ext_vector_type(8))) short bf16x8;
typedef __attribute__((ext_vector_type(4))) float f32x4;

__device__ __forceinline__ short f2bf(float f) {
    unsigned u = __float_as_uint(f);
    u += 0x7FFF + ((u >> 16) & 1);          // round-to-nearest-even
    return (short)(u >> 16);
}

// ---------- init bucket cursors, detect edge dtype ----------
// int64 little-endian with values < 2^31 => every odd 32-bit word is zero.
__global__ __launch_bounds__(256) void k_zero(int* __restrict__ bcur,
                                              const int* __restrict__ ei,
                                              int* __restrict__ flag) {
    int i = blockIdx.x * 256 + threadIdx.x;
    if (i < NB2MAX) bcur[i] = i * BCAP;
    if (i == 0) {
        int o = 0;
        for (int k = 1; k < 64; k += 2) o |= ei[k];
        *flag = (o == 0) ? 1 : 0;
    }
}

// ---------- bucket scatter: single ei pass, LDS-staged, chunk-reserved ----------
// 1024 threads/block; phase A processes 2 edges/thread with int4/int2 loads.
// ebuf[slot] = src | (dst&511)<<23   (requires N < 2^23)
__global__ __launch_bounds__(1024) void k_bucket(const int* __restrict__ ei,
                                                 const int* __restrict__ flag,
                                                 int* __restrict__ bcur,
                                                 int* __restrict__ ebuf,
                                                 int E, int N) {
    __shared__ int lhist[NB2MAX];           // 1 KB
    __shared__ int lbase[NB2MAX];           // 1 KB
    __shared__ int sP[EPW];                 // packed src|ld<<23  32 KB
    __shared__ unsigned short sB[EPW];      // bucket id          16 KB
    const int tid = threadIdx.x;
    if (tid < NB2MAX) lhist[tid] = 0;
    __syncthreads();
    const int m64 = *flag;
    const long long e0 = (long long)blockIdx.x * EPW;
    // phase A: read edges once (2/thread/iter, vectorized), stage in LDS, histogram
    #pragma unroll
    for (int jj = 0; jj < EPW / 2048; ++jj) {
        int p = jj * 1024 + tid;            // pair index within block
        long long e = e0 + 2 * (long long)p;
        int s0 = -1, d0 = -1, s1 = -1, d1 = -1;
        if (e + 1 < E) {
            if (m64) {
                int4 sv = ((const int4*)(ei))[(size_t)(e >> 1)];
                int4 dv = ((const int4*)(ei + 2 * (size_t)E))[(size_t)(e >> 1)];
                s0 = sv.x; s1 = sv.z; d0 = dv.x; d1 = dv.z;
            } else {
                int2 sv = ((const int2*)(ei))[(size_t)(e >> 1)];
                int2 dv = ((const int2*)(ei + (size_t)E))[(size_t)(e >> 1)];
                s0 = sv.x; s1 = sv.y; d0 = dv.x; d1 = dv.y;
            }
        } else if (e < E) {                  // single tail edge
            if (m64) { s0 = ei[2 * (size_t)e]; d0 = ei[2 * ((size_t)E + e)]; }
            else     { s0 = ei[(size_t)e];     d0 = ei[(size_t)E + e]; }
        }
        unsigned short bb0 = 0xFFFF, bb1 = 0xFFFF;
        int pk0 = 0, pk1 = 0;
        if ((unsigned)d0 < (unsigned)N && (unsigned)s0 < (unsigned)N) {
            bb0 = (unsigned short)(d0 >> NPB_SHIFT);
            pk0 = s0 | ((d0 & (NPB - 1)) << 23);
            atomicAdd(&lhist[bb0], 1);
        }
        if ((unsigned)d1 < (unsigned)N && (unsigned)s1 < (unsigned)N) {
            bb1 = (unsigned short)(d1 >> NPB_SHIFT);
            pk1 = s1 | ((d1 & (NPB - 1)) << 23);
            atomicAdd(&lhist[bb1], 1);
        }
        sB[2 * p] = bb0;     sP[2 * p] = pk0;
        sB[2 * p + 1] = bb1; sP[2 * p + 1] = pk1;
    }
    __syncthreads();
    // phase B: reserve dense chunks in the fixed bucket regions
    if (tid < NB2MAX) {
        int c = lhist[tid];
        lbase[tid] = c ? atomicAdd(&bcur[tid], c) : 0;
        lhist[tid] = 0;
    }
    __syncthreads();
    // phase C: scatter from LDS into reserved runs (bounds-guarded)
    #pragma unroll 4
    for (int j = 0; j < EPW / 1024; ++j) {
        int idx = j * 1024 + tid;
        unsigned short bb = sB[idx];
        if (bb != 0xFFFF) {
            int slot = lbase[bb] + atomicAdd(&lhist[bb], 1);
            if (slot < (int)(bb + 1) * BCAP) ebuf[slot] = sP[idx];
        }
    }
}

// ---------- per-bucket counting sort (in place via LDS staging) ----------
// 1024 threads/block. After this, ebuf[b*BCAP ..] is sorted by local dst and
// holds plain src. Emits dinv[n] = rsqrt(deg+1), offp[n] = seg_start | deg<<22.
__global__ __launch_bounds__(1024) void k_sort(int* __restrict__ ebuf,
                                               const int* __restrict__ bcur,
                                               float* __restrict__ dinv,
                                               int* __restrict__ offp, int N) {
    __shared__ int sedge[BCAP];             // 40 KB
    __shared__ int lcnt[NPB];               // 2 KB
    __shared__ int lofs[NPB];               // 2 KB
    __shared__ int sc[NPB];                 // 2 KB
    const int tid = threadIdx.x;
    const int b = blockIdx.x;
    const int start = b * BCAP;
    const int m = min(max(bcur[b] - start, 0), BCAP);

    // vectorized stage: int4 loads (start is 16B-aligned)
    {
        const int4* src4 = (const int4*)(ebuf + start);
        int m4 = m >> 2;
        for (int i = tid; i < m4; i += 1024)
            ((int4*)sedge)[i] = src4[i];
        for (int i = (m4 << 2) + tid; i < m; i += 1024)
            sedge[i] = ebuf[start + i];
    }
    if (tid < NPB) lcnt[tid] = 0;
    __syncthreads();
    for (int i = tid; i < m; i += 1024)
        atomicAdd(&lcnt[((unsigned)sedge[i]) >> 23], 1);
    __syncthreads();
    // inclusive Hillis-Steele scan over NPB=512 counters (tid<512 active,
    // all 1024 threads hit the barriers uniformly)
    int c0 = (tid < NPB) ? lcnt[tid] : 0;
    int val = c0;
    if (tid < NPB) sc[tid] = val;
    __syncthreads();
    #pragma unroll
    for (int d2 = 1; d2 < NPB; d2 <<= 1) {
        int t = (tid < NPB && tid >= d2) ? sc[tid - d2] : 0;
        __syncthreads();
        if (tid < NPB) { val += t; sc[tid] = val; }
        __syncthreads();
    }
    if (tid < NPB) {
        int excl = val - c0;
        lofs[tid] = excl;
        int n = (b << NPB_SHIFT) + tid;
        if (n < N) {
            dinv[n] = rsqrtf((float)c0 + 1.0f);
            offp[n] = (start + excl) | (min(c0, 1023) << 22);  // start+excl < 2^22
        }
    }
    __syncthreads();
    for (int i = tid; i < m; i += 1024) {
        int pk = sedge[i];
        int l = ((unsigned)pk) >> 23;
        int slot = start + atomicAdd(&lofs[l], 1);
        ebuf[slot] = pk & 0x7FFFFF;
    }
}

// ---------- MFMA bf16 GEMM: hs16[n][f] = f16((x@W)[n][f] * dinv[n]) ----------
// block = 256 threads = 4 waves; wave = 32 rows (two 16-row tiles); 128 rows/blk.
// x is staged per 32-col k-chunk into LDS with COALESCED loads (consecutive
// lanes -> consecutive addresses; 8 full-width transactions/wave instead of
// ~32 scattered 16B ones), T14-style async split: chunk kb+1's global loads
// issue into registers before chunk kb's MFMAs, LDS write after the barrier.
// mfma_f32_16x16x32_bf16: A row = lane&15, k = (lane>>4)*8+e ; D col = lane&15,
// row = (lane>>4)*4+reg (HW-verified layout).
#define WLDP 264   // sWt row stride in bf16 units
#define XLDP 36    // sx row stride in floats (144B: 16B-aligned, bank-spread)
__global__ __launch_bounds__(256) void k_gemm(const float* __restrict__ x,
                                              const float* __restrict__ W,
                                              const float* __restrict__ dinv,
                                              _Float16* __restrict__ hs16, int N) {
    __shared__ __align__(16) short sWt[F_OUT * WLDP];   // 16.9 KB
    __shared__ __align__(16) float sx[128 * XLDP];      // 18.4 KB
    const int tid = threadIdx.x;
    const int lane = tid & 63;
    const int wave = tid >> 6;
    const int brow0 = blockIdx.x * 128;
    const int row0 = brow0 + wave * 32;

    // stage W^T (bf16): W is [256][32] row-major
    for (int i = tid; i < F_IN * F_OUT; i += 256) {
        int f = i & 31, k = i >> 5;
        sWt[f * WLDP + k] = f2bf(W[i]);
    }

    const int l15 = lane & 15;
    const int lg  = lane >> 4;          // 0..3
    const short* wb0 = sWt + l15 * WLDP + lg * 8;
    const short* wb1 = sWt + (16 + l15) * WLDP + lg * 8;
    const float* sxa = sx + (wave * 32 + l15) * XLDP + lg * 8;
    const float* sxb = sx + (wave * 32 + 16 + l15) * XLDP + lg * 8;

    // staging geometry: flat i in [0,1024): r = i>>3 (row 0..127), c4 = i&7
    // (float4 col). Consecutive tid -> consecutive c4 within a row.
    const int sr  = tid >> 3;           // this thread's staged rows: sr, sr+? (4 chunks of 256)
    const int sc4 = tid & 7;

    f32x4 acc00 = {0.f, 0.f, 0.f, 0.f};
    f32x4 acc01 = {0.f, 0.f, 0.f, 0.f};
    f32x4 acc10 = {0.f, 0.f, 0.f, 0.f};
    f32x4 acc11 = {0.f, 0.f, 0.f, 0.f};

    // preload chunk 0 into registers
    float4 st[4];
    #pragma unroll
    for (int j = 0; j < 4; ++j) {
        int r = j * 32 + sr;
        int row = min(brow0 + r, N - 1);
        st[j] = ((const float4*)x)[(size_t)row * (F_IN / 4) + sc4];
    }
    // write chunk 0 to LDS
    #pragma unroll
    for (int j = 0; j < 4; ++j)
        *(float4*)(sx + (j * 32 + sr) * XLDP + sc4 * 4) = st[j];
    __syncthreads();

    #pragma unroll
    for (int kb = 0; kb < F_IN / 32; ++kb) {
        // issue chunk kb+1's global loads early (latency hides under MFMA)
        if (kb < F_IN / 32 - 1) {
            #pragma unroll
            for (int j = 0; j < 4; ++j) {
                int r = j * 32 + sr;
                int row = min(brow0 + r, N - 1);
                st[j] = ((const float4*)x)[(size_t)row * (F_IN / 4) + (kb + 1) * 8 + sc4];
            }
        }
        // fragments from LDS (coalesced staging; ds_read_b128 x2 per operand)
        float4 a0 = *(const float4*)(sxa);
        float4 a1 = *(const float4*)(sxa + 4);
        float4 b0 = *(const float4*)(sxb);
        float4 b1 = *(const float4*)(sxb + 4);
        bf16x8 A0, A1;
        A0[0] = f2bf(a0.x); A0[1] = f2bf(a0.y); A0[2] = f2bf(a0.z); A0[3] = f2bf(a0.w);
        A0[4] = f2bf(a1.x); A0[5] = f2bf(a1.y); A0[6] = f2bf(a1.z); A0[7] = f2bf(a1.w);
        A1[0] = f2bf(b0.x); A1[1] = f2bf(b0.y); A1[2] = f2bf(b0.z); A1[3] = f2bf(b0.w);
        A1[4] = f2bf(b1.x); A1[5] = f2bf(b1.y); A1[6] = f2bf(b1.z); A1[7] = f2bf(b1.w);
        bf16x8 B0 = *(const bf16x8*)(wb0 + kb * 32);
        bf16x8 B1 = *(const bf16x8*)(wb1 + kb * 32);
        acc00 = __builtin_amdgcn_mfma_f32_16x16x32_bf16(A0, B0, acc00, 0, 0, 0);
        acc01 = __builtin_amdgcn_mfma_f32_16x16x32_bf16(A0, B1, acc01, 0, 0, 0);
        acc10 = __builtin_amdgcn_mfma_f32_16x16x32_bf16(A1, B0, acc10, 0, 0, 0);
        acc11 = __builtin_amdgcn_mfma_f32_16x16x32_bf16(A1, B1, acc11, 0, 0, 0);
        if (kb < F_IN / 32 - 1) {
            __syncthreads();               // all reads of chunk kb done
            #pragma unroll
            for (int j = 0; j < 4; ++j)
                *(float4*)(sx + (j * 32 + sr) * XLDP + sc4 * 4) = st[j];
            __syncthreads();               // chunk kb+1 visible
        }
    }

    // epilogue: D row = lg*4 + r (within 16-row tile), col = l15 (+16 for tile 1)
    #pragma unroll
    for (int r = 0; r < 4; ++r) {
        int row = row0 + lg * 4 + r;
        if (row < N) {
            float di = dinv[row];
            hs16[(size_t)row * F_OUT + l15]      = (_Float16)(acc00[r] * di);
            hs16[(size_t)row * F_OUT + 16 + l15] = (_Float16)(acc01[r] * di);
        }
        int row2 = row + 16;
        if (row2 < N) {
            float di2 = dinv[row2];
            hs16[(size_t)row2 * F_OUT + l15]      = (_Float16)(acc10[r] * di2);
            hs16[(size_t)row2 * F_OUT + 16 + l15] = (_Float16)(acc11[r] * di2);
        }
    }
}

// ---------- node-parallel gather aggregate over f16 rows: NO atomics ----------
// Natural node order (streaming adj + out). 4 lanes per node; lane q owns one
// uint4 (16B) of the 64B row. Software-pipelined: next batch of 8 adj indices
// loads while the current batch's 8 gathers are in flight.
__global__ __launch_bounds__(256) void k_agg(const _Float16* __restrict__ hs16,
                                             const int* __restrict__ adj,
                                             const int* __restrict__ offp,
                                             const float* __restrict__ dinv,
                                             const float* __restrict__ bias,
                                             float* __restrict__ out, int N) {
    const int tid = threadIdx.x;
    const int n = blockIdx.x * 64 + (tid >> 2);
    const int q = tid & 3;
    if (n >= N) return;

    const int po = offp[n];
    const int st = po & 0x3FFFFF;
    const int deg = ((unsigned)po) >> 22;

    const uint4* __restrict__ h4 = (const uint4*)hs16;
    union U { uint4 u; _Float16 h[8]; };

    float a[8], c[8];
    {   // self-loop term
        U sv; sv.u = h4[(size_t)n * 4 + q];
        #pragma unroll
        for (int i = 0; i < 8; ++i) { a[i] = (float)sv.h[i]; c[i] = 0.f; }
    }

    int k = 0;
    if (deg >= 8) {
        int s[8];
        #pragma unroll
        for (int j = 0; j < 8; ++j) s[j] = adj[st + j];
        while (k + 16 <= deg) {
            U v0, v1, v2, v3, v4, v5, v6, v7;
            v0.u = h4[(size_t)s[0] * 4 + q];
            v1.u = h4[(size_t)s[1] * 4 + q];
            v2.u = h4[(size_t)s[2] * 4 + q];
            v3.u = h4[(size_t)s[3] * 4 + q];
            v4.u = h4[(size_t)s[4] * 4 + q];
            v5.u = h4[(size_t)s[5] * 4 + q];
            v6.u = h4[(size_t)s[6] * 4 + q];
            v7.u = h4[(size_t)s[7] * 4 + q];
            int ns[8];
            #pragma unroll
            for (int j = 0; j < 8; ++j) ns[j] = adj[st + k + 8 + j];
            #pragma unroll
            for (int i = 0; i < 8; ++i) {
                a[i] += ((float)v0.h[i] + (float)v1.h[i]) +
                        ((float)v2.h[i] + (float)v3.h[i]);
                c[i] += ((float)v4.h[i] + (float)v5.h[i]) +
                        ((float)v6.h[i] + (float)v7.h[i]);
            }
            #pragma unroll
            for (int j = 0; j < 8; ++j) s[j] = ns[j];
            k += 8;
        }
        {   // drain the loaded batch (k+8 <= deg invariant)
            U v0, v1, v2, v3, v4, v5, v6, v7;
            v0.u = h4[(size_t)s[0] * 4 + q];
            v1.u = h4[(size_t)s[1] * 4 + q];
            v2.u = h4[(size_t)s[2] * 4 + q];
            v3.u = h4[(size_t)s[3] * 4 + q];
            v4.u = h4[(size_t)s[4] * 4 + q];
            v5.u = h4[(size_t)s[5] * 4 + q];
            v6.u = h4[(size_t)s[6] * 4 + q];
            v7.u = h4[(size_t)s[7] * 4 + q];
            #pragma unroll
            for (int i = 0; i < 8; ++i) {
                a[i] += ((float)v0.h[i] + (float)v1.h[i]) +
                        ((float)v2.h[i] + (float)v3.h[i]);
                c[i] += ((float)v4.h[i] + (float)v5.h[i]) +
                        ((float)v6.h[i] + (float)v7.h[i]);
            }
            k += 8;
        }
    }
    for (; k + 4 <= deg; k += 4) {
        int s0 = adj[st + k];
        int s1 = adj[st + k + 1];
        int s2 = adj[st + k + 2];
        int s3 = adj[st + k + 3];
        U v0, v1, v2, v3;
        v0.u = h4[(size_t)s0 * 4 + q];
        v1.u = h4[(size_t)s1 * 4 + q];
        v2.u = h4[(size_t)s2 * 4 + q];
        v3.u = h4[(size_t)s3 * 4 + q];
        #pragma unroll
        for (int i = 0; i < 8; ++i)
            a[i] += ((float)v0.h[i] + (float)v1.h[i]) +
                    ((float)v2.h[i] + (float)v3.h[i]);
    }
    for (; k < deg; ++k) {
        int s0 = adj[st + k];
        U v0; v0.u = h4[(size_t)s0 * 4 + q];
        #pragma unroll
        for (int i = 0; i < 8; ++i) a[i] += (float)v0.h[i];
    }

    const float di = dinv[n];
    const float4 bv0 = ((const float4*)bias)[q * 2];
    const float4 bv1 = ((const float4*)bias)[q * 2 + 1];
    float4 o0, o1;
    o0.x = bv0.x + di * (a[0] + c[0]); o0.y = bv0.y + di * (a[1] + c[1]);
    o0.z = bv0.z + di * (a[2] + c[2]); o0.w = bv0.w + di * (a[3] + c[3]);
    o1.x = bv1.x + di * (a[4] + c[4]); o1.y = bv1.y + di * (a[5] + c[5]);
    o1.z = bv1.z + di * (a[6] + c[6]); o1.w = bv1.w + di * (a[7] + c[7]);
    float4* op = (float4*)(out + (size_t)n * F_OUT);
    op[q * 2]     = o0;
    op[q * 2 + 1] = o1;
}

extern "C" void kernel_launch(void* const* d_in, const int* in_sizes, int n_in,
                              void* d_out, int out_size, void* d_ws, size_t ws_size,
                              hipStream_t stream) {
    const float* x  = (const float*)d_in[0];
    const int*   ei = (const int*)d_in[1];
    const float* W  = (const float*)d_in[2];
    const float* b  = (const float*)d_in[3];
    float* out = (float*)d_out;

    const int N = in_sizes[0] / F_IN;   // 100000
    const int E = in_sizes[1] / 2;      // 1600000

    // ws layout: hs16 (N*32 f16) | ebuf (NB2MAX*BCAP i32 = 10.5 MB) | dinv (N f32)
    //          | offp (N i32) | bcur (NB2MAX) | flag     (~18 MB of 400 MB)
    _Float16* hs16 = (_Float16*)d_ws;
    int*   ebuf = (int*)(hs16 + (size_t)N * F_OUT);
    float* dinv = (float*)(ebuf + (size_t)NB2MAX * BCAP);
    int*   offp = (int*)(dinv + N);
    int*   bcur = offp + N;
    int*   flag = bcur + NB2MAX;

    const int NB  = (N + NPB - 1) >> NPB_SHIFT;             // 196 (<= NB2MAX)
    const int NBW = (int)(((long long)E + EPW - 1) / EPW);  // 196

    k_zero  <<<1, 256, 0, stream>>>(bcur, ei, flag);
    k_bucket<<<NBW, 1024, 0, stream>>>(ei, flag, bcur, ebuf, E, N);
    k_sort  <<<NB, 1024, 0, stream>>>(ebuf, bcur, dinv, offp, N);
    k_gemm  <<<(N + 127) / 128, 256, 0, stream>>>(x, W, dinv, hs16, N);
    k_agg   <<<(N * 4 + 255) / 256, 256, 0, stream>>>(hs16, ebuf, offp, dinv, b, out, N);
}

// Round 17
// 226.908 us; speedup vs baseline: 1.0997x; 1.0997x over previous
//
#include <hip/hip_runtime.h>

#define F_IN  256
#define F_OUT 32

#define NPB       512        // nodes per bucket (2^9)
#define NPB_SHIFT 9
#define NB2MAX    256        // max buckets: supports N <= 131072
#define EPW       8192       // edges per WG: run len ~ EPW/196 = 42 ints ~ 2.6 lines
#define BCAP      10240      // bucket capacity (mean 8192, +22 sigma)

typedef __attribute__((ext_vector_type(8))) short bf16x8;
typedef __attribute__((ext_vector_type(4))) float f32x4;

__device__ __forceinline__ short f2bf(float f) {
    unsigned u = __float_as_uint(f);
    u += 0x7FFF + ((u >> 16) & 1);          // round-to-nearest-even
    return (short)(u >> 16);
}

// ---------- init bucket cursors, detect edge dtype ----------
// int64 little-endian with values < 2^31 => every odd 32-bit word is zero.
__global__ __launch_bounds__(256) void k_zero(int* __restrict__ bcur,
                                              const int* __restrict__ ei,
                                              int* __restrict__ flag) {
    int i = blockIdx.x * 256 + threadIdx.x;
    if (i < NB2MAX) bcur[i] = i * BCAP;
    if (i == 0) {
        int o = 0;
        for (int k = 1; k < 64; k += 2) o |= ei[k];
        *flag = (o == 0) ? 1 : 0;
    }
}

// ---------- bucket scatter: single ei pass, LDS-staged, chunk-reserved ----------
// 1024 threads/block; phase A processes 2 edges/thread with int4/int2 loads.
// ebuf[slot] = src | (dst&511)<<23   (requires N < 2^23)
__global__ __launch_bounds__(1024) void k_bucket(const int* __restrict__ ei,
                                                 const int* __restrict__ flag,
                                                 int* __restrict__ bcur,
                                                 int* __restrict__ ebuf,
                                                 int E, int N) {
    __shared__ int lhist[NB2MAX];           // 1 KB
    __shared__ int lbase[NB2MAX];           // 1 KB
    __shared__ int sP[EPW];                 // packed src|ld<<23  32 KB
    __shared__ unsigned short sB[EPW];      // bucket id          16 KB
    const int tid = threadIdx.x;
    if (tid < NB2MAX) lhist[tid] = 0;
    __syncthreads();
    const int m64 = *flag;
    const long long e0 = (long long)blockIdx.x * EPW;
    // phase A: read edges once (2/thread/iter, vectorized), stage in LDS, histogram
    #pragma unroll
    for (int jj = 0; jj < EPW / 2048; ++jj) {
        int p = jj * 1024 + tid;            // pair index within block
        long long e = e0 + 2 * (long long)p;
        int s0 = -1, d0 = -1, s1 = -1, d1 = -1;
        if (e + 1 < E) {
            if (m64) {
                int4 sv = ((const int4*)(ei))[(size_t)(e >> 1)];
                int4 dv = ((const int4*)(ei + 2 * (size_t)E))[(size_t)(e >> 1)];
                s0 = sv.x; s1 = sv.z; d0 = dv.x; d1 = dv.z;
            } else {
                int2 sv = ((const int2*)(ei))[(size_t)(e >> 1)];
                int2 dv = ((const int2*)(ei + (size_t)E))[(size_t)(e >> 1)];
                s0 = sv.x; s1 = sv.y; d0 = dv.x; d1 = dv.y;
            }
        } else if (e < E) {                  // single tail edge
            if (m64) { s0 = ei[2 * (size_t)e]; d0 = ei[2 * ((size_t)E + e)]; }
            else     { s0 = ei[(size_t)e];     d0 = ei[(size_t)E + e]; }
        }
        unsigned short bb0 = 0xFFFF, bb1 = 0xFFFF;
        int pk0 = 0, pk1 = 0;
        if ((unsigned)d0 < (unsigned)N && (unsigned)s0 < (unsigned)N) {
            bb0 = (unsigned short)(d0 >> NPB_SHIFT);
            pk0 = s0 | ((d0 & (NPB - 1)) << 23);
            atomicAdd(&lhist[bb0], 1);
        }
        if ((unsigned)d1 < (unsigned)N && (unsigned)s1 < (unsigned)N) {
            bb1 = (unsigned short)(d1 >> NPB_SHIFT);
            pk1 = s1 | ((d1 & (NPB - 1)) << 23);
            atomicAdd(&lhist[bb1], 1);
        }
        sB[2 * p] = bb0;     sP[2 * p] = pk0;
        sB[2 * p + 1] = bb1; sP[2 * p + 1] = pk1;
    }
    __syncthreads();
    // phase B: reserve dense chunks in the fixed bucket regions
    if (tid < NB2MAX) {
        int c = lhist[tid];
        lbase[tid] = c ? atomicAdd(&bcur[tid], c) : 0;
        lhist[tid] = 0;
    }
    __syncthreads();
    // phase C: scatter from LDS into reserved runs (bounds-guarded)
    #pragma unroll 4
    for (int j = 0; j < EPW / 1024; ++j) {
        int idx = j * 1024 + tid;
        unsigned short bb = sB[idx];
        if (bb != 0xFFFF) {
            int slot = lbase[bb] + atomicAdd(&lhist[bb], 1);
            if (slot < (int)(bb + 1) * BCAP) ebuf[slot] = sP[idx];
        }
    }
}

// ---------- per-bucket counting sort (in place via LDS staging) ----------
// 1024 threads/block. After this, ebuf[b*BCAP ..] is sorted by local dst and
// holds plain src. Emits dinv[n] = rsqrt(deg+1), offp[n] = seg_start | deg<<22.
__global__ __launch_bounds__(1024) void k_sort(int* __restrict__ ebuf,
                                               const int* __restrict__ bcur,
                                               float* __restrict__ dinv,
                                               int* __restrict__ offp, int N) {
    __shared__ int sedge[BCAP];             // 40 KB
    __shared__ int lcnt[NPB];               // 2 KB
    __shared__ int lofs[NPB];               // 2 KB
    __shared__ int sc[NPB];                 // 2 KB
    const int tid = threadIdx.x;
    const int b = blockIdx.x;
    const int start = b * BCAP;
    const int m = min(max(bcur[b] - start, 0), BCAP);

    // vectorized stage: int4 loads (start is 16B-aligned)
    {
        const int4* src4 = (const int4*)(ebuf + start);
        int m4 = m >> 2;
        for (int i = tid; i < m4; i += 1024)
            ((int4*)sedge)[i] = src4[i];
        for (int i = (m4 << 2) + tid; i < m; i += 1024)
            sedge[i] = ebuf[start + i];
    }
    if (tid < NPB) lcnt[tid] = 0;
    __syncthreads();
    for (int i = tid; i < m; i += 1024)
        atomicAdd(&lcnt[((unsigned)sedge[i]) >> 23], 1);
    __syncthreads();
    // inclusive Hillis-Steele scan over NPB=512 counters (tid<512 active,
    // all 1024 threads hit the barriers uniformly)
    int c0 = (tid < NPB) ? lcnt[tid] : 0;
    int val = c0;
    if (tid < NPB) sc[tid] = val;
    __syncthreads();
    #pragma unroll
    for (int d2 = 1; d2 < NPB; d2 <<= 1) {
        int t = (tid < NPB && tid >= d2) ? sc[tid - d2] : 0;
        __syncthreads();
        if (tid < NPB) { val += t; sc[tid] = val; }
        __syncthreads();
    }
    if (tid < NPB) {
        int excl = val - c0;
        lofs[tid] = excl;
        int n = (b << NPB_SHIFT) + tid;
        if (n < N) {
            dinv[n] = rsqrtf((float)c0 + 1.0f);
            offp[n] = (start + excl) | (min(c0, 1023) << 22);  // start+excl < 2^22
        }
    }
    __syncthreads();
    for (int i = tid; i < m; i += 1024) {
        int pk = sedge[i];
        int l = ((unsigned)pk) >> 23;
        int slot = start + atomicAdd(&lofs[l], 1);
        ebuf[slot] = pk & 0x7FFFFF;
    }
}

// ---------- MFMA bf16 GEMM: hs16[n][f] = f16((x@W)[n][f] * dinv[n]) ----------
// block = 256 threads = 4 waves; wave = 32 rows (two 16-row tiles); 128 rows/blk.
// W^T staged in LDS as bf16; x read global -> reg -> bf16 with a 2-deep
// register prefetch pipeline (round-15 verified main loop).
// EPILOGUE FIX (round-16 counters: WRITE_SIZE 87 MB for a 6.4 MB output —
// scattered 2-byte stores cause sector RMW): stage acc (x dinv, f16) into
// LDS (reusing sWt after a barrier), then flush with coalesced uint4 stores
// -- 4 consecutive lanes write one full 64B line.
#define WLDP 264   // sWt row stride in bf16 units
#define OLDP 40    // sOut row stride in f16 units (80B = 16B x 5: aligned, bank-spread)
__global__ __launch_bounds__(256) void k_gemm(const float* __restrict__ x,
                                              const float* __restrict__ W,
                                              const float* __restrict__ dinv,
                                              _Float16* __restrict__ hs16, int N) {
    __shared__ __align__(16) short sWt[F_OUT * WLDP];   // 16.9 KB (reused as sOut)
    const int tid = threadIdx.x;
    const int lane = tid & 63;
    const int wave = tid >> 6;
    const int brow0 = blockIdx.x * 128;
    const int row0 = brow0 + wave * 32;

    for (int i = tid; i < F_IN * F_OUT; i += 256) {
        int f = i & 31, k = i >> 5;
        sWt[f * WLDP + k] = f2bf(W[i]);
    }
    __syncthreads();

    const int l15 = lane & 15;
    const int lg  = lane >> 4;          // 0..3
    int ra = row0 + l15;
    int rb = row0 + 16 + l15;
    int rac = min(ra, N - 1);
    int rbc = min(rb, N - 1);

    const float4* xa4 = (const float4*)(x + (size_t)rac * F_IN + lg * 8);
    const float4* xb4 = (const float4*)(x + (size_t)rbc * F_IN + lg * 8);
    const short* wb0 = sWt + l15 * WLDP + lg * 8;
    const short* wb1 = sWt + (16 + l15) * WLDP + lg * 8;

    f32x4 acc00 = {0.f, 0.f, 0.f, 0.f};
    f32x4 acc01 = {0.f, 0.f, 0.f, 0.f};
    f32x4 acc10 = {0.f, 0.f, 0.f, 0.f};
    f32x4 acc11 = {0.f, 0.f, 0.f, 0.f};

    float4 a0 = xa4[0], a1 = xa4[1];
    float4 b0 = xb4[0], b1 = xb4[1];

    #pragma unroll
    for (int kb = 0; kb < F_IN / 32; ++kb) {
        float4 na0, na1, nb0, nb1;
        if (kb < F_IN / 32 - 1) {
            na0 = xa4[(kb + 1) * 8];
            na1 = xa4[(kb + 1) * 8 + 1];
            nb0 = xb4[(kb + 1) * 8];
            nb1 = xb4[(kb + 1) * 8 + 1];
        }
        bf16x8 A0, A1;
        A0[0] = f2bf(a0.x); A0[1] = f2bf(a0.y); A0[2] = f2bf(a0.z); A0[3] = f2bf(a0.w);
        A0[4] = f2bf(a1.x); A0[5] = f2bf(a1.y); A0[6] = f2bf(a1.z); A0[7] = f2bf(a1.w);
        A1[0] = f2bf(b0.x); A1[1] = f2bf(b0.y); A1[2] = f2bf(b0.z); A1[3] = f2bf(b0.w);
        A1[4] = f2bf(b1.x); A1[5] = f2bf(b1.y); A1[6] = f2bf(b1.z); A1[7] = f2bf(b1.w);
        bf16x8 B0 = *(const bf16x8*)(wb0 + kb * 32);
        bf16x8 B1 = *(const bf16x8*)(wb1 + kb * 32);
        acc00 = __builtin_amdgcn_mfma_f32_16x16x32_bf16(A0, B0, acc00, 0, 0, 0);
        acc01 = __builtin_amdgcn_mfma_f32_16x16x32_bf16(A0, B1, acc01, 0, 0, 0);
        acc10 = __builtin_amdgcn_mfma_f32_16x16x32_bf16(A1, B0, acc10, 0, 0, 0);
        acc11 = __builtin_amdgcn_mfma_f32_16x16x32_bf16(A1, B1, acc11, 0, 0, 0);
        a0 = na0; a1 = na1; b0 = nb0; b1 = nb1;
    }

    // ---- epilogue: LDS bounce for coalesced full-line hs16 writes ----
    __syncthreads();                        // all sWt reads done; reuse as sOut
    _Float16* sOut = (_Float16*)sWt;        // [128][OLDP] f16 = 10.2 KB
    #pragma unroll
    for (int r = 0; r < 4; ++r) {
        int lr0 = wave * 32 + lg * 4 + r;   // local row, tile 0
        float di0 = dinv[min(brow0 + lr0, N - 1)];
        sOut[lr0 * OLDP + l15]      = (_Float16)(acc00[r] * di0);
        sOut[lr0 * OLDP + 16 + l15] = (_Float16)(acc01[r] * di0);
        int lr1 = lr0 + 16;                 // local row, tile 1
        float di1 = dinv[min(brow0 + lr1, N - 1)];
        sOut[lr1 * OLDP + l15]      = (_Float16)(acc10[r] * di1);
        sOut[lr1 * OLDP + 16 + l15] = (_Float16)(acc11[r] * di1);
    }
    __syncthreads();
    // flush: 512 x 16B chunks; 4 consecutive lanes cover one 64B row/line
    #pragma unroll
    for (int it = 0; it < 2; ++it) {
        int chunk = it * 256 + tid;         // 0..511
        int lr = chunk >> 2;                // 0..127
        int c  = chunk & 3;                 // 16B chunk within row
        int grow = brow0 + lr;
        if (grow < N) {
            uint4 v = *(const uint4*)(sOut + lr * OLDP + c * 8);
            ((uint4*)(hs16 + (size_t)grow * F_OUT))[c] = v;
        }
    }
}

// ---------- node-parallel gather aggregate over f16 rows: NO atomics ----------
// Natural node order (streaming adj + out). 4 lanes per node; lane q owns one
// uint4 (16B) of the 64B row. Software-pipelined: next batch of 8 adj indices
// loads while the current batch's 8 gathers are in flight.
__global__ __launch_bounds__(256) void k_agg(const _Float16* __restrict__ hs16,
                                             const int* __restrict__ adj,
                                             const int* __restrict__ offp,
                                             const float* __restrict__ dinv,
                                             const float* __restrict__ bias,
                                             float* __restrict__ out, int N) {
    const int tid = threadIdx.x;
    const int n = blockIdx.x * 64 + (tid >> 2);
    const int q = tid & 3;
    if (n >= N) return;

    const int po = offp[n];
    const int st = po & 0x3FFFFF;
    const int deg = ((unsigned)po) >> 22;

    const uint4* __restrict__ h4 = (const uint4*)hs16;
    union U { uint4 u; _Float16 h[8]; };

    float a[8], c[8];
    {   // self-loop term
        U sv; sv.u = h4[(size_t)n * 4 + q];
        #pragma unroll
        for (int i = 0; i < 8; ++i) { a[i] = (float)sv.h[i]; c[i] = 0.f; }
    }

    int k = 0;
    if (deg >= 8) {
        int s[8];
        #pragma unroll
        for (int j = 0; j < 8; ++j) s[j] = adj[st + j];
        while (k + 16 <= deg) {
            U v0, v1, v2, v3, v4, v5, v6, v7;
            v0.u = h4[(size_t)s[0] * 4 + q];
            v1.u = h4[(size_t)s[1] * 4 + q];
            v2.u = h4[(size_t)s[2] * 4 + q];
            v3.u = h4[(size_t)s[3] * 4 + q];
            v4.u = h4[(size_t)s[4] * 4 + q];
            v5.u = h4[(size_t)s[5] * 4 + q];
            v6.u = h4[(size_t)s[6] * 4 + q];
            v7.u = h4[(size_t)s[7] * 4 + q];
            int ns[8];
            #pragma unroll
            for (int j = 0; j < 8; ++j) ns[j] = adj[st + k + 8 + j];
            #pragma unroll
            for (int i = 0; i < 8; ++i) {
                a[i] += ((float)v0.h[i] + (float)v1.h[i]) +
                        ((float)v2.h[i] + (float)v3.h[i]);
                c[i] += ((float)v4.h[i] + (float)v5.h[i]) +
                        ((float)v6.h[i] + (float)v7.h[i]);
            }
            #pragma unroll
            for (int j = 0; j < 8; ++j) s[j] = ns[j];
            k += 8;
        }
        {   // drain the loaded batch (k+8 <= deg invariant)
            U v0, v1, v2, v3, v4, v5, v6, v7;
            v0.u = h4[(size_t)s[0] * 4 + q];
            v1.u = h4[(size_t)s[1] * 4 + q];
            v2.u = h4[(size_t)s[2] * 4 + q];
            v3.u = h4[(size_t)s[3] * 4 + q];
            v4.u = h4[(size_t)s[4] * 4 + q];
            v5.u = h4[(size_t)s[5] * 4 + q];
            v6.u = h4[(size_t)s[6] * 4 + q];
            v7.u = h4[(size_t)s[7] * 4 + q];
            #pragma unroll
            for (int i = 0; i < 8; ++i) {
                a[i] += ((float)v0.h[i] + (float)v1.h[i]) +
                        ((float)v2.h[i] + (float)v3.h[i]);
                c[i] += ((float)v4.h[i] + (float)v5.h[i]) +
                        ((float)v6.h[i] + (float)v7.h[i]);
            }
            k += 8;
        }
    }
    for (; k + 4 <= deg; k += 4) {
        int s0 = adj[st + k];
        int s1 = adj[st + k + 1];
        int s2 = adj[st + k + 2];
        int s3 = adj[st + k + 3];
        U v0, v1, v2, v3;
        v0.u = h4[(size_t)s0 * 4 + q];
        v1.u = h4[(size_t)s1 * 4 + q];
        v2.u = h4[(size_t)s2 * 4 + q];
        v3.u = h4[(size_t)s3 * 4 + q];
        #pragma unroll
        for (int i = 0; i < 8; ++i)
            a[i] += ((float)v0.h[i] + (float)v1.h[i]) +
                    ((float)v2.h[i] + (float)v3.h[i]);
    }
    for (; k < deg; ++k) {
        int s0 = adj[st + k];
        U v0; v0.u = h4[(size_t)s0 * 4 + q];
        #pragma unroll
        for (int i = 0; i < 8; ++i) a[i] += (float)v0.h[i];
    }

    const float di = dinv[n];
    const float4 bv0 = ((const float4*)bias)[q * 2];
    const float4 bv1 = ((const float4*)bias)[q * 2 + 1];
    float4 o0, o1;
    o0.x = bv0.x + di * (a[0] + c[0]); o0.y = bv0.y + di * (a[1] + c[1]);
    o0.z = bv0.z + di * (a[2] + c[2]); o0.w = bv0.w + di * (a[3] + c[3]);
    o1.x = bv1.x + di * (a[4] + c[4]); o1.y = bv1.y + di * (a[5] + c[5]);
    o1.z = bv1.z + di * (a[6] + c[6]); o1.w = bv1.w + di * (a[7] + c[7]);
    float4* op = (float4*)(out + (size_t)n * F_OUT);
    op[q * 2]     = o0;
    op[q * 2 + 1] = o1;
}

extern "C" void kernel_launch(void* const* d_in, const int* in_sizes, int n_in,
                              void* d_out, int out_size, void* d_ws, size_t ws_size,
                              hipStream_t stream) {
    const float* x  = (const float*)d_in[0];
    const int*   ei = (const int*)d_in[1];
    const float* W  = (const float*)d_in[2];
    const float* b  = (const float*)d_in[3];
    float* out = (float*)d_out;

    const int N = in_sizes[0] / F_IN;   // 100000
    const int E = in_sizes[1] / 2;      // 1600000

    // ws layout: hs16 (N*32 f16) | ebuf (NB2MAX*BCAP i32 = 10.5 MB) | dinv (N f32)
    //          | offp (N i32) | bcur (NB2MAX) | flag     (~18 MB of 400 MB)
    _Float16* hs16 = (_Float16*)d_ws;
    int*   ebuf = (int*)(hs16 + (size_t)N * F_OUT);
    float* dinv = (float*)(ebuf + (size_t)NB2MAX * BCAP);
    int*   offp = (int*)(dinv + N);
    int*   bcur = offp + N;
    int*   flag = bcur + NB2MAX;

    const int NB  = (N + NPB - 1) >> NPB_SHIFT;             // 196 (<= NB2MAX)
    const int NBW = (int)(((long long)E + EPW - 1) / EPW);  // 196

    k_zero  <<<1, 256, 0, stream>>>(bcur, ei, flag);
    k_bucket<<<NBW, 1024, 0, stream>>>(ei, flag, bcur, ebuf, E, N);
    k_sort  <<<NB, 1024, 0, stream>>>(ebuf, bcur, dinv, offp, N);
    k_gemm  <<<(N + 127) / 128, 256, 0, stream>>>(x, W, dinv, hs16, N);
    k_agg   <<<(N * 4 + 255) / 256, 256, 0, stream>>>(hs16, ebuf, offp, dinv, b, out, N);
}

// Round 18
// 225.924 us; speedup vs baseline: 1.1044x; 1.0044x over previous
//
#include <hip/hip_runtime.h>

#define F_IN  256
#define F_OUT 32

#define NPB       256        // nodes per bucket (2^8)
#define NPB_SHIFT 8
#define NBK       512        // max buckets: supports N <= 131072
#define EPW       8192       // edges per staging WG: run len ~ 8192/391 = 21 ints ~ 84B
#define BCAP      5376       // bucket capacity (mean 4092, +20 sigma)

typedef __attribute__((ext_vector_type(8))) short bf16x8;
typedef __attribute__((ext_vector_type(4))) float f32x4;

__device__ __forceinline__ short f2bf(float f) {
    unsigned u = __float_as_uint(f);
    u += 0x7FFF + ((u >> 16) & 1);          // round-to-nearest-even
    return (short)(u >> 16);
}

// ---------- init bucket cursors, detect edge dtype ----------
// int64 little-endian with values < 2^31 => every odd 32-bit word is zero.
__global__ __launch_bounds__(256) void k_zero(int* __restrict__ bcur,
                                              const int* __restrict__ ei,
                                              int* __restrict__ flag) {
    int i = blockIdx.x * 256 + threadIdx.x;
    if (i < NBK) bcur[i] = i * BCAP;
    if (i == 0) {
        int o = 0;
        for (int k = 1; k < 64; k += 2) o |= ei[k];
        *flag = (o == 0) ? 1 : 0;
    }
}

// ---------- bucket scatter: single ei pass, LDS-staged, chunk-reserved ----------
// 1024 threads/block; phase A processes 2 edges/thread with int4/int2 loads.
// ebuf[slot] = src | (dst&255)<<23   (requires N < 2^23)
__global__ __launch_bounds__(1024) void k_bucket(const int* __restrict__ ei,
                                                 const int* __restrict__ flag,
                                                 int* __restrict__ bcur,
                                                 int* __restrict__ ebuf,
                                                 int E, int N) {
    __shared__ int lhist[NBK];              // 2 KB
    __shared__ int lbase[NBK];              // 2 KB
    __shared__ int sP[EPW];                 // packed src|ld<<23  32 KB
    __shared__ unsigned short sB[EPW];      // bucket id          16 KB
    const int tid = threadIdx.x;
    if (tid < NBK) lhist[tid] = 0;
    __syncthreads();
    const int m64 = *flag;
    const long long e0 = (long long)blockIdx.x * EPW;
    // phase A: read edges once (2/thread/iter, vectorized), stage in LDS, histogram
    #pragma unroll
    for (int jj = 0; jj < EPW / 2048; ++jj) {
        int p = jj * 1024 + tid;            // pair index within block
        long long e = e0 + 2 * (long long)p;
        int s0 = -1, d0 = -1, s1 = -1, d1 = -1;
        if (e + 1 < E) {
            if (m64) {
                int4 sv = ((const int4*)(ei))[(size_t)(e >> 1)];
                int4 dv = ((const int4*)(ei + 2 * (size_t)E))[(size_t)(e >> 1)];
                s0 = sv.x; s1 = sv.z; d0 = dv.x; d1 = dv.z;
            } else {
                int2 sv = ((const int2*)(ei))[(size_t)(e >> 1)];
                int2 dv = ((const int2*)(ei + (size_t)E))[(size_t)(e >> 1)];
                s0 = sv.x; s1 = sv.y; d0 = dv.x; d1 = dv.y;
            }
        } else if (e < E) {                  // single tail edge
            if (m64) { s0 = ei[2 * (size_t)e]; d0 = ei[2 * ((size_t)E + e)]; }
            else     { s0 = ei[(size_t)e];     d0 = ei[(size_t)E + e]; }
        }
        unsigned short bb0 = 0xFFFF, bb1 = 0xFFFF;
        int pk0 = 0, pk1 = 0;
        if ((unsigned)d0 < (unsigned)N && (unsigned)s0 < (unsigned)N) {
            bb0 = (unsigned short)(d0 >> NPB_SHIFT);
            pk0 = s0 | ((d0 & (NPB - 1)) << 23);
            atomicAdd(&lhist[bb0], 1);
        }
        if ((unsigned)d1 < (unsigned)N && (unsigned)s1 < (unsigned)N) {
            bb1 = (unsigned short)(d1 >> NPB_SHIFT);
            pk1 = s1 | ((d1 & (NPB - 1)) << 23);
            atomicAdd(&lhist[bb1], 1);
        }
        sB[2 * p] = bb0;     sP[2 * p] = pk0;
        sB[2 * p + 1] = bb1; sP[2 * p + 1] = pk1;
    }
    __syncthreads();
    // phase B: reserve dense chunks in the fixed bucket regions
    if (tid < NBK) {
        int c = lhist[tid];
        lbase[tid] = c ? atomicAdd(&bcur[tid], c) : 0;
        lhist[tid] = 0;
    }
    __syncthreads();
    // phase C: scatter from LDS into reserved runs (bounds-guarded)
    #pragma unroll 4
    for (int j = 0; j < EPW / 1024; ++j) {
        int idx = j * 1024 + tid;
        unsigned short bb = sB[idx];
        if (bb != 0xFFFF) {
            int slot = lbase[bb] + atomicAdd(&lhist[bb], 1);
            if (slot < (int)(bb + 1) * BCAP) ebuf[slot] = sP[idx];
        }
    }
}

// ---------- per-bucket counting sort (in place via LDS staging) ----------
// 391 blocks x 512 threads (better CU coverage + multi-block overlap;
// LDS ~24.5 KB). After this, ebuf[b*BCAP ..] is sorted by local dst and
// holds plain src. Emits dinv[n] = rsqrt(deg+1), offp[n] = seg_start | deg<<22.
__global__ __launch_bounds__(512) void k_sort(int* __restrict__ ebuf,
                                              const int* __restrict__ bcur,
                                              float* __restrict__ dinv,
                                              int* __restrict__ offp, int N) {
    __shared__ int sedge[BCAP];             // 21 KB
    __shared__ int lcnt[NPB];               // 1 KB
    __shared__ int lofs[NPB];               // 1 KB
    __shared__ int sc[NPB];                 // 1 KB
    const int tid = threadIdx.x;
    const int b = blockIdx.x;
    const int start = b * BCAP;
    const int m = min(max(bcur[b] - start, 0), BCAP);

    // vectorized stage: int4 loads (start is 16B-aligned)
    {
        const int4* src4 = (const int4*)(ebuf + start);
        int m4 = m >> 2;
        for (int i = tid; i < m4; i += 512)
            ((int4*)sedge)[i] = src4[i];
        for (int i = (m4 << 2) + tid; i < m; i += 512)
            sedge[i] = ebuf[start + i];
    }
    if (tid < NPB) lcnt[tid] = 0;
    __syncthreads();
    for (int i = tid; i < m; i += 512)
        atomicAdd(&lcnt[((unsigned)sedge[i]) >> 23], 1);
    __syncthreads();
    // inclusive Hillis-Steele scan over NPB=256 counters (tid<256 active,
    // all 512 threads hit the barriers uniformly)
    int c0 = (tid < NPB) ? lcnt[tid] : 0;
    int val = c0;
    if (tid < NPB) sc[tid] = val;
    __syncthreads();
    #pragma unroll
    for (int d2 = 1; d2 < NPB; d2 <<= 1) {
        int t = (tid < NPB && tid >= d2) ? sc[tid - d2] : 0;
        __syncthreads();
        if (tid < NPB) { val += t; sc[tid] = val; }
        __syncthreads();
    }
    if (tid < NPB) {
        int excl = val - c0;
        lofs[tid] = excl;
        int n = (b << NPB_SHIFT) + tid;
        if (n < N) {
            dinv[n] = rsqrtf((float)c0 + 1.0f);
            offp[n] = (start + excl) | (min(c0, 1023) << 22);  // start+excl < 2^22
        }
    }
    __syncthreads();
    for (int i = tid; i < m; i += 512) {
        int pk = sedge[i];
        int l = ((unsigned)pk) >> 23;
        int slot = start + atomicAdd(&lofs[l], 1);
        ebuf[slot] = pk & 0x7FFFFF;
    }
}

// ---------- MFMA bf16 GEMM: hs16[n][f] = f16((x@W)[n][f] * dinv[n]) ----------
// block = 256 threads = 4 waves; wave = 32 rows (two 16-row tiles); 128 rows/blk.
// W^T staged in LDS as bf16; x read global -> reg -> bf16 with a 2-deep
// register prefetch pipeline. Epilogue: LDS bounce, coalesced uint4 stores.
#define WLDP 264   // sWt row stride in bf16 units
#define OLDP 40    // sOut row stride in f16 units
__global__ __launch_bounds__(256) void k_gemm(const float* __restrict__ x,
                                              const float* __restrict__ W,
                                              const float* __restrict__ dinv,
                                              _Float16* __restrict__ hs16, int N) {
    __shared__ __align__(16) short sWt[F_OUT * WLDP];   // 16.9 KB (reused as sOut)
    const int tid = threadIdx.x;
    const int lane = tid & 63;
    const int wave = tid >> 6;
    const int brow0 = blockIdx.x * 128;
    const int row0 = brow0 + wave * 32;

    for (int i = tid; i < F_IN * F_OUT; i += 256) {
        int f = i & 31, k = i >> 5;
        sWt[f * WLDP + k] = f2bf(W[i]);
    }
    __syncthreads();

    const int l15 = lane & 15;
    const int lg  = lane >> 4;          // 0..3
    int ra = row0 + l15;
    int rb = row0 + 16 + l15;
    int rac = min(ra, N - 1);
    int rbc = min(rb, N - 1);

    const float4* xa4 = (const float4*)(x + (size_t)rac * F_IN + lg * 8);
    const float4* xb4 = (const float4*)(x + (size_t)rbc * F_IN + lg * 8);
    const short* wb0 = sWt + l15 * WLDP + lg * 8;
    const short* wb1 = sWt + (16 + l15) * WLDP + lg * 8;

    f32x4 acc00 = {0.f, 0.f, 0.f, 0.f};
    f32x4 acc01 = {0.f, 0.f, 0.f, 0.f};
    f32x4 acc10 = {0.f, 0.f, 0.f, 0.f};
    f32x4 acc11 = {0.f, 0.f, 0.f, 0.f};

    float4 a0 = xa4[0], a1 = xa4[1];
    float4 b0 = xb4[0], b1 = xb4[1];

    #pragma unroll
    for (int kb = 0; kb < F_IN / 32; ++kb) {
        float4 na0, na1, nb0, nb1;
        if (kb < F_IN / 32 - 1) {
            na0 = xa4[(kb + 1) * 8];
            na1 = xa4[(kb + 1) * 8 + 1];
            nb0 = xb4[(kb + 1) * 8];
            nb1 = xb4[(kb + 1) * 8 + 1];
        }
        bf16x8 A0, A1;
        A0[0] = f2bf(a0.x); A0[1] = f2bf(a0.y); A0[2] = f2bf(a0.z); A0[3] = f2bf(a0.w);
        A0[4] = f2bf(a1.x); A0[5] = f2bf(a1.y); A0[6] = f2bf(a1.z); A0[7] = f2bf(a1.w);
        A1[0] = f2bf(b0.x); A1[1] = f2bf(b0.y); A1[2] = f2bf(b0.z); A1[3] = f2bf(b0.w);
        A1[4] = f2bf(b1.x); A1[5] = f2bf(b1.y); A1[6] = f2bf(b1.z); A1[7] = f2bf(b1.w);
        bf16x8 B0 = *(const bf16x8*)(wb0 + kb * 32);
        bf16x8 B1 = *(const bf16x8*)(wb1 + kb * 32);
        acc00 = __builtin_amdgcn_mfma_f32_16x16x32_bf16(A0, B0, acc00, 0, 0, 0);
        acc01 = __builtin_amdgcn_mfma_f32_16x16x32_bf16(A0, B1, acc01, 0, 0, 0);
        acc10 = __builtin_amdgcn_mfma_f32_16x16x32_bf16(A1, B0, acc10, 0, 0, 0);
        acc11 = __builtin_amdgcn_mfma_f32_16x16x32_bf16(A1, B1, acc11, 0, 0, 0);
        a0 = na0; a1 = na1; b0 = nb0; b1 = nb1;
    }

    // ---- epilogue: LDS bounce for coalesced full-line hs16 writes ----
    __syncthreads();                        // all sWt reads done; reuse as sOut
    _Float16* sOut = (_Float16*)sWt;        // [128][OLDP] f16 = 10.2 KB
    #pragma unroll
    for (int r = 0; r < 4; ++r) {
        int lr0 = wave * 32 + lg * 4 + r;   // local row, tile 0
        float di0 = dinv[min(brow0 + lr0, N - 1)];
        sOut[lr0 * OLDP + l15]      = (_Float16)(acc00[r] * di0);
        sOut[lr0 * OLDP + 16 + l15] = (_Float16)(acc01[r] * di0);
        int lr1 = lr0 + 16;                 // local row, tile 1
        float di1 = dinv[min(brow0 + lr1, N - 1)];
        sOut[lr1 * OLDP + l15]      = (_Float16)(acc10[r] * di1);
        sOut[lr1 * OLDP + 16 + l15] = (_Float16)(acc11[r] * di1);
    }
    __syncthreads();
    // flush: 512 x 16B chunks; 4 consecutive lanes cover one 64B row/line
    #pragma unroll
    for (int it = 0; it < 2; ++it) {
        int chunk = it * 256 + tid;         // 0..511
        int lr = chunk >> 2;                // 0..127
        int c  = chunk & 3;                 // 16B chunk within row
        int grow = brow0 + lr;
        if (grow < N) {
            uint4 v = *(const uint4*)(sOut + lr * OLDP + c * 8);
            ((uint4*)(hs16 + (size_t)grow * F_OUT))[c] = v;
        }
    }
}

// ---------- node-parallel gather aggregate over f16 rows: NO atomics ----------
// Natural node order (streaming adj + out). 4 lanes per node; lane q owns one
// uint4 (16B) of the 64B row. Software-pipelined: next batch of 8 adj indices
// loads while the current batch's 8 gathers are in flight.
__global__ __launch_bounds__(256) void k_agg(const _Float16* __restrict__ hs16,
                                             const int* __restrict__ adj,
                                             const int* __restrict__ offp,
                                             const float* __restrict__ dinv,
                                             const float* __restrict__ bias,
                                             float* __restrict__ out, int N) {
    const int tid = threadIdx.x;
    const int n = blockIdx.x * 64 + (tid >> 2);
    const int q = tid & 3;
    if (n >= N) return;

    const int po = offp[n];
    const int st = po & 0x3FFFFF;
    const int deg = ((unsigned)po) >> 22;

    const uint4* __restrict__ h4 = (const uint4*)hs16;
    union U { uint4 u; _Float16 h[8]; };

    float a[8], c[8];
    {   // self-loop term
        U sv; sv.u = h4[(size_t)n * 4 + q];
        #pragma unroll
        for (int i = 0; i < 8; ++i) { a[i] = (float)sv.h[i]; c[i] = 0.f; }
    }

    int k = 0;
    if (deg >= 8) {
        int s[8];
        #pragma unroll
        for (int j = 0; j < 8; ++j) s[j] = adj[st + j];
        while (k + 16 <= deg) {
            U v0, v1, v2, v3, v4, v5, v6, v7;
            v0.u = h4[(size_t)s[0] * 4 + q];
            v1.u = h4[(size_t)s[1] * 4 + q];
            v2.u = h4[(size_t)s[2] * 4 + q];
            v3.u = h4[(size_t)s[3] * 4 + q];
            v4.u = h4[(size_t)s[4] * 4 + q];
            v5.u = h4[(size_t)s[5] * 4 + q];
            v6.u = h4[(size_t)s[6] * 4 + q];
            v7.u = h4[(size_t)s[7] * 4 + q];
            int ns[8];
            #pragma unroll
            for (int j = 0; j < 8; ++j) ns[j] = adj[st + k + 8 + j];
            #pragma unroll
            for (int i = 0; i < 8; ++i) {
                a[i] += ((float)v0.h[i] + (float)v1.h[i]) +
                        ((float)v2.h[i] + (float)v3.h[i]);
                c[i] += ((float)v4.h[i] + (float)v5.h[i]) +
                        ((float)v6.h[i] + (float)v7.h[i]);
            }
            #pragma unroll
            for (int j = 0; j < 8; ++j) s[j] = ns[j];
            k += 8;
        }
        {   // drain the loaded batch (k+8 <= deg invariant)
            U v0, v1, v2, v3, v4, v5, v6, v7;
            v0.u = h4[(size_t)s[0] * 4 + q];
            v1.u = h4[(size_t)s[1] * 4 + q];
            v2.u = h4[(size_t)s[2] * 4 + q];
            v3.u = h4[(size_t)s[3] * 4 + q];
            v4.u = h4[(size_t)s[4] * 4 + q];
            v5.u = h4[(size_t)s[5] * 4 + q];
            v6.u = h4[(size_t)s[6] * 4 + q];
            v7.u = h4[(size_t)s[7] * 4 + q];
            #pragma unroll
            for (int i = 0; i < 8; ++i) {
                a[i] += ((float)v0.h[i] + (float)v1.h[i]) +
                        ((float)v2.h[i] + (float)v3.h[i]);
                c[i] += ((float)v4.h[i] + (float)v5.h[i]) +
                        ((float)v6.h[i] + (float)v7.h[i]);
            }
            k += 8;
        }
    }
    for (; k + 4 <= deg; k += 4) {
        int s0 = adj[st + k];
        int s1 = adj[st + k + 1];
        int s2 = adj[st + k + 2];
        int s3 = adj[st + k + 3];
        U v0, v1, v2, v3;
        v0.u = h4[(size_t)s0 * 4 + q];
        v1.u = h4[(size_t)s1 * 4 + q];
        v2.u = h4[(size_t)s2 * 4 + q];
        v3.u = h4[(size_t)s3 * 4 + q];
        #pragma unroll
        for (int i = 0; i < 8; ++i)
            a[i] += ((float)v0.h[i] + (float)v1.h[i]) +
                    ((float)v2.h[i] + (float)v3.h[i]);
    }
    for (; k < deg; ++k) {
        int s0 = adj[st + k];
        U v0; v0.u = h4[(size_t)s0 * 4 + q];
        #pragma unroll
        for (int i = 0; i < 8; ++i) a[i] += (float)v0.h[i];
    }

    const float di = dinv[n];
    const float4 bv0 = ((const float4*)bias)[q * 2];
    const float4 bv1 = ((const float4*)bias)[q * 2 + 1];
    float4 o0, o1;
    o0.x = bv0.x + di * (a[0] + c[0]); o0.y = bv0.y + di * (a[1] + c[1]);
    o0.z = bv0.z + di * (a[2] + c[2]); o0.w = bv0.w + di * (a[3] + c[3]);
    o1.x = bv1.x + di * (a[4] + c[4]); o1.y = bv1.y + di * (a[5] + c[5]);
    o1.z = bv1.z + di * (a[6] + c[6]); o1.w = bv1.w + di * (a[7] + c[7]);
    float4* op = (float4*)(out + (size_t)n * F_OUT);
    op[q * 2]     = o0;
    op[q * 2 + 1] = o1;
}

extern "C" void kernel_launch(void* const* d_in, const int* in_sizes, int n_in,
                              void* d_out, int out_size, void* d_ws, size_t ws_size,
                              hipStream_t stream) {
    const float* x  = (const float*)d_in[0];
    const int*   ei = (const int*)d_in[1];
    const float* W  = (const float*)d_in[2];
    const float* b  = (const float*)d_in[3];
    float* out = (float*)d_out;

    const int N = in_sizes[0] / F_IN;   // 100000
    const int E = in_sizes[1] / 2;      // 1600000

    // ws layout: hs16 (N*32 f16) | ebuf (NBK*BCAP i32 = 11 MB) | dinv (N f32)
    //          | offp (N i32) | bcur (NBK) | flag     (~18.5 MB of 400 MB)
    _Float16* hs16 = (_Float16*)d_ws;
    int*   ebuf = (int*)(hs16 + (size_t)N * F_OUT);
    float* dinv = (float*)(ebuf + (size_t)NBK * BCAP);
    int*   offp = (int*)(dinv + N);
    int*   bcur = offp + N;
    int*   flag = bcur + NBK;

    const int NB  = (N + NPB - 1) >> NPB_SHIFT;             // 391 (<= NBK)
    const int NBW = (int)(((long long)E + EPW - 1) / EPW);  // 196

    k_zero  <<<(NBK + 255) / 256, 256, 0, stream>>>(bcur, ei, flag);
    k_bucket<<<NBW, 1024, 0, stream>>>(ei, flag, bcur, ebuf, E, N);
    k_sort  <<<NB, 512, 0, stream>>>(ebuf, bcur, dinv, offp, N);
    k_gemm  <<<(N + 127) / 128, 256, 0, stream>>>(x, W, dinv, hs16, N);
    k_agg   <<<(N * 4 + 255) / 256, 256, 0, stream>>>(hs16, ebuf, offp, dinv, b, out, N);
}

// Round 19
// 224.057 us; speedup vs baseline: 1.1136x; 1.0083x over previous
//
#include <hip/hip_runtime.h>

#define F_IN  256
#define F_OUT 32

#define NPB       256        // nodes per bucket (2^8)
#define NPB_SHIFT 8
#define NBK       512        // max buckets: supports N <= 131072
#define EPW       8192       // edges per staging WG: run len ~ 8192/391 = 21 ints ~ 84B
#define BCAP      5376       // bucket capacity (mean 4092, +20 sigma)

typedef __attribute__((ext_vector_type(8))) short bf16x8;
typedef __attribute__((ext_vector_type(4))) float f32x4;

__device__ __forceinline__ short f2bf(float f) {
    unsigned u = __float_as_uint(f);
    u += 0x7FFF + ((u >> 16) & 1);          // round-to-nearest-even
    return (short)(u >> 16);
}

// ---------- init bucket cursors, detect edge dtype ----------
// int64 little-endian with values < 2^31 => every odd 32-bit word is zero.
__global__ __launch_bounds__(256) void k_zero(int* __restrict__ bcur,
                                              const int* __restrict__ ei,
                                              int* __restrict__ flag) {
    int i = blockIdx.x * 256 + threadIdx.x;
    if (i < NBK) bcur[i] = i * BCAP;
    if (i == 0) {
        int o = 0;
        for (int k = 1; k < 64; k += 2) o |= ei[k];
        *flag = (o == 0) ? 1 : 0;
    }
}

// ---------- bucket scatter: single ei pass, LDS-staged, chunk-reserved ----------
// 1024 threads/block; phase A processes 2 edges/thread with int4/int2 loads.
// ebuf[slot] = src | (dst&255)<<23   (requires N < 2^23)
__global__ __launch_bounds__(1024) void k_bucket(const int* __restrict__ ei,
                                                 const int* __restrict__ flag,
                                                 int* __restrict__ bcur,
                                                 int* __restrict__ ebuf,
                                                 int E, int N) {
    __shared__ int lhist[NBK];              // 2 KB
    __shared__ int lbase[NBK];              // 2 KB
    __shared__ int sP[EPW];                 // packed src|ld<<23  32 KB
    __shared__ unsigned short sB[EPW];      // bucket id          16 KB
    const int tid = threadIdx.x;
    if (tid < NBK) lhist[tid] = 0;
    __syncthreads();
    const int m64 = *flag;
    const long long e0 = (long long)blockIdx.x * EPW;
    // phase A: read edges once (2/thread/iter, vectorized), stage in LDS, histogram
    #pragma unroll
    for (int jj = 0; jj < EPW / 2048; ++jj) {
        int p = jj * 1024 + tid;            // pair index within block
        long long e = e0 + 2 * (long long)p;
        int s0 = -1, d0 = -1, s1 = -1, d1 = -1;
        if (e + 1 < E) {
            if (m64) {
                int4 sv = ((const int4*)(ei))[(size_t)(e >> 1)];
                int4 dv = ((const int4*)(ei + 2 * (size_t)E))[(size_t)(e >> 1)];
                s0 = sv.x; s1 = sv.z; d0 = dv.x; d1 = dv.z;
            } else {
                int2 sv = ((const int2*)(ei))[(size_t)(e >> 1)];
                int2 dv = ((const int2*)(ei + (size_t)E))[(size_t)(e >> 1)];
                s0 = sv.x; s1 = sv.y; d0 = dv.x; d1 = dv.y;
            }
        } else if (e < E) {                  // single tail edge
            if (m64) { s0 = ei[2 * (size_t)e]; d0 = ei[2 * ((size_t)E + e)]; }
            else     { s0 = ei[(size_t)e];     d0 = ei[(size_t)E + e]; }
        }
        unsigned short bb0 = 0xFFFF, bb1 = 0xFFFF;
        int pk0 = 0, pk1 = 0;
        if ((unsigned)d0 < (unsigned)N && (unsigned)s0 < (unsigned)N) {
            bb0 = (unsigned short)(d0 >> NPB_SHIFT);
            pk0 = s0 | ((d0 & (NPB - 1)) << 23);
            atomicAdd(&lhist[bb0], 1);
        }
        if ((unsigned)d1 < (unsigned)N && (unsigned)s1 < (unsigned)N) {
            bb1 = (unsigned short)(d1 >> NPB_SHIFT);
            pk1 = s1 | ((d1 & (NPB - 1)) << 23);
            atomicAdd(&lhist[bb1], 1);
        }
        sB[2 * p] = bb0;     sP[2 * p] = pk0;
        sB[2 * p + 1] = bb1; sP[2 * p + 1] = pk1;
    }
    __syncthreads();
    // phase B: reserve dense chunks in the fixed bucket regions
    if (tid < NBK) {
        int c = lhist[tid];
        lbase[tid] = c ? atomicAdd(&bcur[tid], c) : 0;
        lhist[tid] = 0;
    }
    __syncthreads();
    // phase C: scatter from LDS into reserved runs (bounds-guarded)
    #pragma unroll 4
    for (int j = 0; j < EPW / 1024; ++j) {
        int idx = j * 1024 + tid;
        unsigned short bb = sB[idx];
        if (bb != 0xFFFF) {
            int slot = lbase[bb] + atomicAdd(&lhist[bb], 1);
            if (slot < (int)(bb + 1) * BCAP) ebuf[slot] = sP[idx];
        }
    }
}

// ---------- per-bucket counting sort (in place via LDS staging) ----------
// 391 blocks x 512 threads. After this, ebuf[b*BCAP ..] is sorted by local dst
// and holds plain src. Emits dinv[n] = rsqrt(deg+1), offp[n] = start | deg<<22.
__global__ __launch_bounds__(512) void k_sort(int* __restrict__ ebuf,
                                              const int* __restrict__ bcur,
                                              float* __restrict__ dinv,
                                              int* __restrict__ offp, int N) {
    __shared__ int sedge[BCAP];             // 21 KB
    __shared__ int lcnt[NPB];               // 1 KB
    __shared__ int lofs[NPB];               // 1 KB
    __shared__ int sc[NPB];                 // 1 KB
    const int tid = threadIdx.x;
    const int b = blockIdx.x;
    const int start = b * BCAP;
    const int m = min(max(bcur[b] - start, 0), BCAP);

    // vectorized stage: int4 loads (start is 16B-aligned)
    {
        const int4* src4 = (const int4*)(ebuf + start);
        int m4 = m >> 2;
        for (int i = tid; i < m4; i += 512)
            ((int4*)sedge)[i] = src4[i];
        for (int i = (m4 << 2) + tid; i < m; i += 512)
            sedge[i] = ebuf[start + i];
    }
    if (tid < NPB) lcnt[tid] = 0;
    __syncthreads();
    for (int i = tid; i < m; i += 512)
        atomicAdd(&lcnt[((unsigned)sedge[i]) >> 23], 1);
    __syncthreads();
    // inclusive Hillis-Steele scan over NPB=256 counters (tid<256 active,
    // all 512 threads hit the barriers uniformly)
    int c0 = (tid < NPB) ? lcnt[tid] : 0;
    int val = c0;
    if (tid < NPB) sc[tid] = val;
    __syncthreads();
    #pragma unroll
    for (int d2 = 1; d2 < NPB; d2 <<= 1) {
        int t = (tid < NPB && tid >= d2) ? sc[tid - d2] : 0;
        __syncthreads();
        if (tid < NPB) { val += t; sc[tid] = val; }
        __syncthreads();
    }
    if (tid < NPB) {
        int excl = val - c0;
        lofs[tid] = excl;
        int n = (b << NPB_SHIFT) + tid;
        if (n < N) {
            dinv[n] = rsqrtf((float)c0 + 1.0f);
            offp[n] = (start + excl) | (min(c0, 1023) << 22);  // start+excl < 2^22
        }
    }
    __syncthreads();
    for (int i = tid; i < m; i += 512) {
        int pk = sedge[i];
        int l = ((unsigned)pk) >> 23;
        int slot = start + atomicAdd(&lofs[l], 1);
        ebuf[slot] = pk & 0x7FFFFF;
    }
}

// ---------- MFMA bf16 GEMM: hs16[n][f] = f16((x@W)[n][f] * dinv[n]) ----------
// block = 256 threads = 4 waves; wave = 32 rows (two 16-row tiles); 128 rows/blk.
// 4-DEEP register prefetch pipeline (2 chunks in flight, 128B/lane): x loads
// are LLC-latency-bound (round-16 counters: ~2 TB/s), so doubling bytes in
// flight should ~double effective load throughput.
#define WLDP 264   // sWt row stride in bf16 units
#define OLDP 40    // sOut row stride in f16 units
__global__ __launch_bounds__(256) void k_gemm(const float* __restrict__ x,
                                              const float* __restrict__ W,
                                              const float* __restrict__ dinv,
                                              _Float16* __restrict__ hs16, int N) {
    __shared__ __align__(16) short sWt[F_OUT * WLDP];   // 16.9 KB (reused as sOut)
    const int tid = threadIdx.x;
    const int lane = tid & 63;
    const int wave = tid >> 6;
    const int brow0 = blockIdx.x * 128;
    const int row0 = brow0 + wave * 32;

    for (int i = tid; i < F_IN * F_OUT; i += 256) {
        int f = i & 31, k = i >> 5;
        sWt[f * WLDP + k] = f2bf(W[i]);
    }
    __syncthreads();

    const int l15 = lane & 15;
    const int lg  = lane >> 4;          // 0..3
    int ra = row0 + l15;
    int rb = row0 + 16 + l15;
    int rac = min(ra, N - 1);
    int rbc = min(rb, N - 1);

    const float4* xa4 = (const float4*)(x + (size_t)rac * F_IN + lg * 8);
    const float4* xb4 = (const float4*)(x + (size_t)rbc * F_IN + lg * 8);
    const short* wb0 = sWt + l15 * WLDP + lg * 8;
    const short* wb1 = sWt + (16 + l15) * WLDP + lg * 8;

    f32x4 acc00 = {0.f, 0.f, 0.f, 0.f};
    f32x4 acc01 = {0.f, 0.f, 0.f, 0.f};
    f32x4 acc10 = {0.f, 0.f, 0.f, 0.f};
    f32x4 acc11 = {0.f, 0.f, 0.f, 0.f};

    // chunks 0 and 1 preloaded; loop unrolls by 2 with named buffers (static idx)
    float4 p0 = xa4[0], p1 = xa4[1], p2 = xb4[0], p3 = xb4[1];
    float4 q0 = xa4[8], q1 = xa4[9], q2 = xb4[8], q3 = xb4[9];

    #pragma unroll
    for (int kb = 0; kb < F_IN / 32; kb += 2) {
        float4 t0, t1, t2, t3, u0, u1, u2, u3;
        if (kb + 2 < F_IN / 32) {
            t0 = xa4[(kb + 2) * 8]; t1 = xa4[(kb + 2) * 8 + 1];
            t2 = xb4[(kb + 2) * 8]; t3 = xb4[(kb + 2) * 8 + 1];
        }
        if (kb + 3 < F_IN / 32) {
            u0 = xa4[(kb + 3) * 8]; u1 = xa4[(kb + 3) * 8 + 1];
            u2 = xb4[(kb + 3) * 8]; u3 = xb4[(kb + 3) * 8 + 1];
        }
        // chunk kb (from p*)
        {
            bf16x8 A0, A1;
            A0[0] = f2bf(p0.x); A0[1] = f2bf(p0.y); A0[2] = f2bf(p0.z); A0[3] = f2bf(p0.w);
            A0[4] = f2bf(p1.x); A0[5] = f2bf(p1.y); A0[6] = f2bf(p1.z); A0[7] = f2bf(p1.w);
            A1[0] = f2bf(p2.x); A1[1] = f2bf(p2.y); A1[2] = f2bf(p2.z); A1[3] = f2bf(p2.w);
            A1[4] = f2bf(p3.x); A1[5] = f2bf(p3.y); A1[6] = f2bf(p3.z); A1[7] = f2bf(p3.w);
            bf16x8 B0 = *(const bf16x8*)(wb0 + kb * 32);
            bf16x8 B1 = *(const bf16x8*)(wb1 + kb * 32);
            acc00 = __builtin_amdgcn_mfma_f32_16x16x32_bf16(A0, B0, acc00, 0, 0, 0);
            acc01 = __builtin_amdgcn_mfma_f32_16x16x32_bf16(A0, B1, acc01, 0, 0, 0);
            acc10 = __builtin_amdgcn_mfma_f32_16x16x32_bf16(A1, B0, acc10, 0, 0, 0);
            acc11 = __builtin_amdgcn_mfma_f32_16x16x32_bf16(A1, B1, acc11, 0, 0, 0);
        }
        // chunk kb+1 (from q*)
        {
            bf16x8 A0, A1;
            A0[0] = f2bf(q0.x); A0[1] = f2bf(q0.y); A0[2] = f2bf(q0.z); A0[3] = f2bf(q0.w);
            A0[4] = f2bf(q1.x); A0[5] = f2bf(q1.y); A0[6] = f2bf(q1.z); A0[7] = f2bf(q1.w);
            A1[0] = f2bf(q2.x); A1[1] = f2bf(q2.y); A1[2] = f2bf(q2.z); A1[3] = f2bf(q2.w);
            A1[4] = f2bf(q3.x); A1[5] = f2bf(q3.y); A1[6] = f2bf(q3.z); A1[7] = f2bf(q3.w);
            bf16x8 B0 = *(const bf16x8*)(wb0 + (kb + 1) * 32);
            bf16x8 B1 = *(const bf16x8*)(wb1 + (kb + 1) * 32);
            acc00 = __builtin_amdgcn_mfma_f32_16x16x32_bf16(A0, B0, acc00, 0, 0, 0);
            acc01 = __builtin_amdgcn_mfma_f32_16x16x32_bf16(A0, B1, acc01, 0, 0, 0);
            acc10 = __builtin_amdgcn_mfma_f32_16x16x32_bf16(A1, B0, acc10, 0, 0, 0);
            acc11 = __builtin_amdgcn_mfma_f32_16x16x32_bf16(A1, B1, acc11, 0, 0, 0);
        }
        p0 = t0; p1 = t1; p2 = t2; p3 = t3;
        q0 = u0; q1 = u1; q2 = u2; q3 = u3;
    }

    // ---- epilogue: LDS bounce for coalesced full-line hs16 writes ----
    __syncthreads();                        // all sWt reads done; reuse as sOut
    _Float16* sOut = (_Float16*)sWt;        // [128][OLDP] f16 = 10.2 KB
    #pragma unroll
    for (int r = 0; r < 4; ++r) {
        int lr0 = wave * 32 + lg * 4 + r;   // local row, tile 0
        float di0 = dinv[min(brow0 + lr0, N - 1)];
        sOut[lr0 * OLDP + l15]      = (_Float16)(acc00[r] * di0);
        sOut[lr0 * OLDP + 16 + l15] = (_Float16)(acc01[r] * di0);
        int lr1 = lr0 + 16;                 // local row, tile 1
        float di1 = dinv[min(brow0 + lr1, N - 1)];
        sOut[lr1 * OLDP + l15]      = (_Float16)(acc10[r] * di1);
        sOut[lr1 * OLDP + 16 + l15] = (_Float16)(acc11[r] * di1);
    }
    __syncthreads();
    // flush: 512 x 16B chunks; 4 consecutive lanes cover one 64B row/line
    #pragma unroll
    for (int it = 0; it < 2; ++it) {
        int chunk = it * 256 + tid;         // 0..511
        int lr = chunk >> 2;                // 0..127
        int c  = chunk & 3;                 // 16B chunk within row
        int grow = brow0 + lr;
        if (grow < N) {
            uint4 v = *(const uint4*)(sOut + lr * OLDP + c * 8);
            ((uint4*)(hs16 + (size_t)grow * F_OUT))[c] = v;
        }
    }
}

// ---------- node-parallel gather aggregate over f16 rows: NO atomics ----------
// Uniform masked 8-batches: every batch issues exactly 8 clamped-index gathers
// (weights 0/1 via fma), next batch's adj indices prefetch while gathers are
// in flight. No shallow-ILP tail paths.
__global__ __launch_bounds__(256) void k_agg(const _Float16* __restrict__ hs16,
                                             const int* __restrict__ adj,
                                             const int* __restrict__ offp,
                                             const float* __restrict__ dinv,
                                             const float* __restrict__ bias,
                                             float* __restrict__ out, int N) {
    const int tid = threadIdx.x;
    const int n = blockIdx.x * 64 + (tid >> 2);
    const int q = tid & 3;
    if (n >= N) return;

    const int po = offp[n];
    const int st = po & 0x3FFFFF;
    const int deg = ((unsigned)po) >> 22;

    const uint4* __restrict__ h4 = (const uint4*)hs16;
    union U { uint4 u; _Float16 h[8]; };

    float a[8], c[8];
    {   // self-loop term
        U sv; sv.u = h4[(size_t)n * 4 + q];
        #pragma unroll
        for (int i = 0; i < 8; ++i) { a[i] = (float)sv.h[i]; c[i] = 0.f; }
    }

    if (deg > 0) {
        const int last = st + deg - 1;
        int s[8];
        #pragma unroll
        for (int j = 0; j < 8; ++j) s[j] = adj[min(st + j, last)];
        int k = 0;
        while (true) {
            U v[8];
            #pragma unroll
            for (int j = 0; j < 8; ++j) v[j].u = h4[(size_t)s[j] * 4 + q];
            const bool more = (k + 8 < deg);
            int ns[8];
            if (more) {
                #pragma unroll
                for (int j = 0; j < 8; ++j) ns[j] = adj[min(st + k + 8 + j, last)];
            }
            #pragma unroll
            for (int j = 0; j < 8; ++j) {
                const float w = (k + j < deg) ? 1.f : 0.f;
                #pragma unroll
                for (int i = 0; i < 8; ++i) {
                    const float t = w * (float)v[j].h[i];
                    if (j < 4) a[i] += t; else c[i] += t;
                }
            }
            if (!more) break;
            #pragma unroll
            for (int j = 0; j < 8; ++j) s[j] = ns[j];
            k += 8;
        }
    }

    const float di = dinv[n];
    const float4 bv0 = ((const float4*)bias)[q * 2];
    const float4 bv1 = ((const float4*)bias)[q * 2 + 1];
    float4 o0, o1;
    o0.x = bv0.x + di * (a[0] + c[0]); o0.y = bv0.y + di * (a[1] + c[1]);
    o0.z = bv0.z + di * (a[2] + c[2]); o0.w = bv0.w + di * (a[3] + c[3]);
    o1.x = bv1.x + di * (a[4] + c[4]); o1.y = bv1.y + di * (a[5] + c[5]);
    o1.z = bv1.z + di * (a[6] + c[6]); o1.w = bv1.w + di * (a[7] + c[7]);
    float4* op = (float4*)(out + (size_t)n * F_OUT);
    op[q * 2]     = o0;
    op[q * 2 + 1] = o1;
}

extern "C" void kernel_launch(void* const* d_in, const int* in_sizes, int n_in,
                              void* d_out, int out_size, void* d_ws, size_t ws_size,
                              hipStream_t stream) {
    const float* x  = (const float*)d_in[0];
    const int*   ei = (const int*)d_in[1];
    const float* W  = (const float*)d_in[2];
    const float* b  = (const float*)d_in[3];
    float* out = (float*)d_out;

    const int N = in_sizes[0] / F_IN;   // 100000
    const int E = in_sizes[1] / 2;      // 1600000

    // ws layout: hs16 (N*32 f16) | ebuf (NBK*BCAP i32 = 11 MB) | dinv (N f32)
    //          | offp (N i32) | bcur (NBK) | flag     (~18.5 MB of 400 MB)
    _Float16* hs16 = (_Float16*)d_ws;
    int*   ebuf = (int*)(hs16 + (size_t)N * F_OUT);
    float* dinv = (float*)(ebuf + (size_t)NBK * BCAP);
    int*   offp = (int*)(dinv + N);
    int*   bcur = offp + N;
    int*   flag = bcur + NBK;

    const int NB  = (N + NPB - 1) >> NPB_SHIFT;             // 391 (<= NBK)
    const int NBW = (int)(((long long)E + EPW - 1) / EPW);  // 196

    k_zero  <<<(NBK + 255) / 256, 256, 0, stream>>>(bcur, ei, flag);
    k_bucket<<<NBW, 1024, 0, stream>>>(ei, flag, bcur, ebuf, E, N);
    k_sort  <<<NB, 512, 0, stream>>>(ebuf, bcur, dinv, offp, N);
    k_gemm  <<<(N + 127) / 128, 256, 0, stream>>>(x, W, dinv, hs16, N);
    k_agg   <<<(N * 4 + 255) / 256, 256, 0, stream>>>(hs16, ebuf, offp, dinv, b, out, N);
}